// Round 1
// baseline (1633.756 us; speedup 1.0000x reference)
//
#include <hip/hip_runtime.h>

#define IMG    384
#define CDIM   60
#define NHEADS 6
#define DH     10
#define NTOK   64
#define NWIN   48
#define WNUM   (NWIN * NWIN)   // 2304

__device__ __forceinline__ int regionOf(int x) {
    // slices on 384: [0,376) -> 0, [376,380) -> 1, [380,384) -> 2
    return (x < IMG - 8) ? 0 : ((x < IMG - 4) ? 1 : 2);
}

__global__ __launch_bounds__(256, 2)
void swin_fused(const float* __restrict__ img,
                const float* __restrict__ qw,    // [60][180]
                const float* __restrict__ bias,  // [225][6]
                const float* __restrict__ pw,    // [60][60]
                const float* __restrict__ pb,    // [60]
                float* __restrict__ out)
{
    __shared__ float xs[NTOK * 61];   // window input  [n][c] stride 61
    __shared__ float os[NTOK * 61];   // attn output   [n][c] stride 61
    __shared__ float qT[DH * 68];     // per-head q^T  [dd][n] stride 68 (q pre-scaled)
    __shared__ float kT[DH * 68];
    __shared__ float vT[DH * 68];
    __shared__ float S [NTOK * 68];   // scores [i][j] stride 68; reused as ys at end

    const int tid = threadIdx.x;
    const int bid = blockIdx.x;
    const int b   = bid / WNUM;
    const int wi  = bid - b * WNUM;
    const int wh  = wi / NWIN;
    const int ww  = wi - wh * NWIN;

    // ---------------- load window (cyclic shift folded into address) ------------
    for (int idx = tid; idx < NTOK * CDIM; idx += 256) {
        int n = idx / CDIM;
        int c = idx - n * CDIM;
        int yi = n >> 3, xi = n & 7;
        int sh = wh * 8 + yi + 4; if (sh >= IMG) sh -= IMG;
        int sw = ww * 8 + xi + 4; if (sw >= IMG) sw -= IMG;
        xs[n * 61 + c] = img[(((size_t)b * IMG + sh) * IMG + sw) * CDIM + c];
    }
    __syncthreads();

    const int to  = tid & 63;                                   // token (QKV/proj)
    const int grp = __builtin_amdgcn_readfirstlane(tid >> 6);   // wave id 0..3 (SGPR)

    const int ti = tid >> 4;        // attn tile coords
    const int tj = tid & 15;
    const int i0 = ti * 4, j0 = tj * 4;

    const int r  = tid >> 2;        // softmax row, 4 lanes per row
    const int q4 = tid & 3;
    const int jb = q4 * 16;

    for (int h = 0; h < NHEADS; ++h) {
        // ------------- QKV slice for head h: 30 cols split across 4 waves -------
        {
            const int oc0 = grp * 8;
            int colg[8];
            #pragma unroll
            for (int k = 0; k < 8; ++k) {
                int oc = oc0 + k; if (oc > 29) oc = 29;   // clamp (grp3 has 6 cols)
                int which = oc / 10;
                int dd    = oc - which * 10;
                colg[k]   = which * 60 + h * 10 + dd;     // wave-uniform
            }
            float acc[8] = {0.f,0.f,0.f,0.f,0.f,0.f,0.f,0.f};
            for (int c = 0; c < CDIM; ++c) {
                float xv = xs[to * 61 + c];
                const float* wrow = qw + c * 180;
                #pragma unroll
                for (int k = 0; k < 8; ++k)
                    acc[k] = fmaf(xv, wrow[colg[k]], acc[k]);   // s_load weights
            }
            #pragma unroll
            for (int k = 0; k < 8; ++k) {
                int oc = oc0 + k;
                if (oc < 30) {
                    int which = oc / 10;
                    int dd    = oc - which * 10;
                    float v = acc[k];
                    if (which == 0) v *= 0.31622776601683794f;  // 1/sqrt(10) on q
                    float* dst = (which == 0) ? qT : (which == 1) ? kT : vT;
                    dst[dd * 68 + to] = v;
                }
            }
        }
        __syncthreads();

        // ------------- S = q k^T + bias + mask (4x4 register tile) -------------
        {
            float sacc[16];
            #pragma unroll
            for (int k = 0; k < 16; ++k) sacc[k] = 0.f;
            #pragma unroll
            for (int dd = 0; dd < DH; ++dd) {
                float4 qv = *(const float4*)&qT[dd * 68 + i0];
                float4 kv = *(const float4*)&kT[dd * 68 + j0];
                sacc[ 0] = fmaf(qv.x, kv.x, sacc[ 0]);
                sacc[ 1] = fmaf(qv.x, kv.y, sacc[ 1]);
                sacc[ 2] = fmaf(qv.x, kv.z, sacc[ 2]);
                sacc[ 3] = fmaf(qv.x, kv.w, sacc[ 3]);
                sacc[ 4] = fmaf(qv.y, kv.x, sacc[ 4]);
                sacc[ 5] = fmaf(qv.y, kv.y, sacc[ 5]);
                sacc[ 6] = fmaf(qv.y, kv.z, sacc[ 6]);
                sacc[ 7] = fmaf(qv.y, kv.w, sacc[ 7]);
                sacc[ 8] = fmaf(qv.z, kv.x, sacc[ 8]);
                sacc[ 9] = fmaf(qv.z, kv.y, sacc[ 9]);
                sacc[10] = fmaf(qv.z, kv.z, sacc[10]);
                sacc[11] = fmaf(qv.z, kv.w, sacc[11]);
                sacc[12] = fmaf(qv.w, kv.x, sacc[12]);
                sacc[13] = fmaf(qv.w, kv.y, sacc[13]);
                sacc[14] = fmaf(qv.w, kv.z, sacc[14]);
                sacc[15] = fmaf(qv.w, kv.w, sacc[15]);
            }
            // precompute region ids for the 4 j's of this tile
            int pj4[4];
            #pragma unroll
            for (int bb = 0; bb < 4; ++bb) {
                int j = j0 + bb;
                int yj = j >> 3, xj = j & 7;
                pj4[bb] = regionOf(wh * 8 + yj) * 3 + regionOf(ww * 8 + xj);
            }
            #pragma unroll
            for (int a = 0; a < 4; ++a) {
                int i = i0 + a;
                int yi = i >> 3, xi = i & 7;
                int pi = regionOf(wh * 8 + yi) * 3 + regionOf(ww * 8 + xi);
                float4 sv;
                float* svp = &sv.x;
                #pragma unroll
                for (int bb = 0; bb < 4; ++bb) {
                    int j = j0 + bb;
                    int yj = j >> 3, xj = j & 7;
                    int ridx = (yi - yj + 7) * 15 + (xi - xj + 7);
                    float v = sacc[a * 4 + bb] + bias[ridx * 6 + h];
                    if (pi != pj4[bb]) v -= 100.0f;
                    svp[bb] = v;
                }
                *(float4*)&S[i * 68 + j0] = sv;
            }
        }
        __syncthreads();

        // ------------- softmax (rows, 4 lanes/row) fused with PV ----------------
        {
            float4 t0 = *(const float4*)&S[r * 68 + jb];
            float4 t1 = *(const float4*)&S[r * 68 + jb + 4];
            float4 t2 = *(const float4*)&S[r * 68 + jb + 8];
            float4 t3 = *(const float4*)&S[r * 68 + jb + 12];
            float p[16];
            p[0]=t0.x; p[1]=t0.y; p[2]=t0.z; p[3]=t0.w;
            p[4]=t1.x; p[5]=t1.y; p[6]=t1.z; p[7]=t1.w;
            p[8]=t2.x; p[9]=t2.y; p[10]=t2.z; p[11]=t2.w;
            p[12]=t3.x; p[13]=t3.y; p[14]=t3.z; p[15]=t3.w;

            float m = p[0];
            #pragma unroll
            for (int k = 1; k < 16; ++k) m = fmaxf(m, p[k]);
            m = fmaxf(m, __shfl_xor(m, 1));
            m = fmaxf(m, __shfl_xor(m, 2));

            float ssum = 0.f;
            #pragma unroll
            for (int k = 0; k < 16; ++k) { p[k] = __expf(p[k] - m); ssum += p[k]; }
            ssum += __shfl_xor(ssum, 1);
            ssum += __shfl_xor(ssum, 2);
            float rinv = 1.0f / ssum;

            #pragma unroll
            for (int dd = 0; dd < DH; ++dd) {
                const float* vrow = &vT[dd * 68 + jb];
                float4 v0 = *(const float4*)&vrow[0];
                float4 v1 = *(const float4*)&vrow[4];
                float4 v2 = *(const float4*)&vrow[8];
                float4 v3 = *(const float4*)&vrow[12];
                float a = 0.f;
                a = fmaf(p[ 0], v0.x, a); a = fmaf(p[ 1], v0.y, a);
                a = fmaf(p[ 2], v0.z, a); a = fmaf(p[ 3], v0.w, a);
                a = fmaf(p[ 4], v1.x, a); a = fmaf(p[ 5], v1.y, a);
                a = fmaf(p[ 6], v1.z, a); a = fmaf(p[ 7], v1.w, a);
                a = fmaf(p[ 8], v2.x, a); a = fmaf(p[ 9], v2.y, a);
                a = fmaf(p[10], v2.z, a); a = fmaf(p[11], v2.w, a);
                a = fmaf(p[12], v3.x, a); a = fmaf(p[13], v3.y, a);
                a = fmaf(p[14], v3.z, a); a = fmaf(p[15], v3.w, a);
                a += __shfl_xor(a, 1);
                a += __shfl_xor(a, 2);
                if ((dd & 3) == q4)
                    os[r * 61 + h * 10 + dd] = a * rinv;   // each entry written once
            }
        }
        __syncthreads();   // protect qT/kT/vT/S for next head
    }

    // ---------------- projection: Y = os @ pw + pb  (15 cols per wave) ----------
    {
        const int col0 = grp * 15;
        float pacc[15];
        #pragma unroll
        for (int k = 0; k < 15; ++k) pacc[k] = pb[col0 + k];
        for (int c = 0; c < CDIM; ++c) {
            float xv = os[to * 61 + c];
            const float* wrow = pw + c * 60 + col0;
            #pragma unroll
            for (int k = 0; k < 15; ++k)
                pacc[k] = fmaf(xv, wrow[k], pacc[k]);   // s_load weights
        }
        #pragma unroll
        for (int k = 0; k < 15; ++k)
            S[to * 61 + col0 + k] = pacc[k];            // ys staged in S buffer
    }
    __syncthreads();

    // ---------------- store (reverse shift == same coords as load) --------------
    for (int idx = tid; idx < NTOK * CDIM; idx += 256) {
        int n = idx / CDIM;
        int c = idx - n * CDIM;
        int yi = n >> 3, xi = n & 7;
        int sh = wh * 8 + yi + 4; if (sh >= IMG) sh -= IMG;
        int sw = ww * 8 + xi + 4; if (sw >= IMG) sw -= IMG;
        out[(((size_t)b * IMG + sh) * IMG + sw) * CDIM + c] = S[n * 61 + c];
    }
}

extern "C" void kernel_launch(void* const* d_in, const int* in_sizes, int n_in,
                              void* d_out, int out_size, void* d_ws, size_t ws_size,
                              hipStream_t stream) {
    const float* img  = (const float*)d_in[0];
    const float* qw   = (const float*)d_in[1];
    const float* bias = (const float*)d_in[2];
    const float* pw   = (const float*)d_in[3];
    const float* pb   = (const float*)d_in[4];
    float* out = (float*)d_out;

    dim3 grid(4 * WNUM);   // 9216 windows
    dim3 block(256);
    swin_fused<<<grid, block, 0, stream>>>(img, qw, bias, pw, pb, out);
}

// Round 2
// 489.845 us; speedup vs baseline: 3.3353x; 3.3353x over previous
//
#include <hip/hip_runtime.h>

#define IMG    384
#define CDIM   60
#define NHEADS 6
#define DH     10
#define NWIN   48
#define WNUM   (NWIN * NWIN)   // 2304

typedef short  bf16x8 __attribute__((ext_vector_type(8)));
typedef float  f32x4  __attribute__((ext_vector_type(4)));

union Frag { int4 i4; bf16x8 b8; };

#define MFMA(a, b, c) __builtin_amdgcn_mfma_f32_16x16x32_bf16((a), (b), (c), 0, 0, 0)

__device__ __forceinline__ unsigned short f2bf(float f) {
    unsigned int u = __float_as_uint(f);
    unsigned int r = u + 0x7fffu + ((u >> 16) & 1u);
    return (unsigned short)(r >> 16);
}

__device__ __forceinline__ int regionOf(int x) {
    return (x < IMG - 8) ? 0 : ((x < IMG - 4) ? 1 : 2);
}

// ---------------------------------------------------------------------------
// Prep: swizzle qkv_w / proj_w into MFMA B-fragment order (bf16) in d_ws.
//   qkv frags:  24 frags (n=0..11, ks=0..1), frag = 64 lanes x 16B -> 24 KB @ 0
//   proj frags:  8 frags (n=0..3,  ks=0..1)                        ->  8 KB @ 24576
// B-frag lane l: col = n*16 + (l&15), k = ks*32 + (l>>4)*8 + jj  (jj = 0..7)
// ---------------------------------------------------------------------------
__global__ void swin_prep(const float* __restrict__ qw,   // [60][180]
                          const float* __restrict__ pw,   // [60][60]
                          unsigned char* __restrict__ ws)
{
    int t = blockIdx.x * 256 + threadIdx.x;        // 0..2047
    if (t >= 2048) return;
    unsigned short vals[8];
    if (t < 1536) {
        int lane = t & 63, f = t >> 6;
        int n = f >> 1, ks = f & 1;
        int col = n * 16 + (lane & 15);
        int k0  = ks * 32 + (lane >> 4) * 8;
        #pragma unroll
        for (int jj = 0; jj < 8; ++jj) {
            int k = k0 + jj;
            float v = (col < 180 && k < 60) ? qw[k * 180 + col] : 0.f;
            vals[jj] = f2bf(v);
        }
        int4 p;
        p.x = vals[0] | (vals[1] << 16);  p.y = vals[2] | (vals[3] << 16);
        p.z = vals[4] | (vals[5] << 16);  p.w = vals[6] | (vals[7] << 16);
        *(int4*)(ws + t * 16) = p;
    } else {
        int t2 = t - 1536;
        int lane = t2 & 63, f = t2 >> 6;
        int n = f >> 1, ks = f & 1;
        int col = n * 16 + (lane & 15);
        int k0  = ks * 32 + (lane >> 4) * 8;
        #pragma unroll
        for (int jj = 0; jj < 8; ++jj) {
            int k = k0 + jj;
            float v = (col < 60 && k < 60) ? pw[k * 60 + col] : 0.f;
            vals[jj] = f2bf(v);
        }
        int4 p;
        p.x = vals[0] | (vals[1] << 16);  p.y = vals[2] | (vals[3] << 16);
        p.z = vals[4] | (vals[5] << 16);  p.w = vals[6] | (vals[7] << 16);
        *(int4*)(ws + 24576 + t2 * 16) = p;
    }
}

// ---------------------------------------------------------------------------
// Main fused kernel: one 256-thread block per window. 3 barriers total.
// ---------------------------------------------------------------------------
__global__ __launch_bounds__(256, 2)
void swin_mfma(const float* __restrict__ img,
               const float* __restrict__ biasm,   // [225][6]
               const float* __restrict__ pbias,   // [60]
               const unsigned char* __restrict__ ws,
               float* __restrict__ out)
{
    // LDS: 58,880 B total (2 blocks/CU)
    __shared__ unsigned short uni[64 * 72];    // xb [64][72]  U  P-slabs [4][16][72]
    __shared__ unsigned short qall[64 * 104];  // [tok][h*16 + d]   (k 10..15 garbage, masked in reg)
    __shared__ unsigned short kall[64 * 104];
    __shared__ unsigned short vall[96 * 72];   // [h*16 + d][tok]   (d 10..15 rows zeroed)
    __shared__ unsigned short osb[64 * 72];    // [tok][h*10 + d]   (cols 60..63 zeroed)

    const int tid  = threadIdx.x;
    const int lane = tid & 63;
    const int wid  = __builtin_amdgcn_readfirstlane(tid >> 6);  // wave 0..3
    const int l15  = lane & 15;
    const int g    = lane >> 4;

    const int bid = blockIdx.x;
    const int b   = bid / WNUM;
    const int wi  = bid - b * WNUM;
    const int wh  = wi / NWIN;
    const int ww  = wi - wh * NWIN;

    // ---- phase 0: load window (shift folded in) as bf16; zero pads ---------
    for (int t = tid; t < 64 * 64; t += 256) {
        int n = t >> 6, c = t & 63;
        float v = 0.f;
        if (c < 60) {
            int yi = n >> 3, xi = n & 7;
            int sh = wh * 8 + yi + 4; if (sh >= IMG) sh -= IMG;
            int sw = ww * 8 + xi + 4; if (sw >= IMG) sw -= IMG;
            v = img[((b * IMG + sh) * IMG + sw) * CDIM + c];
        }
        uni[n * 72 + c] = f2bf(v);
    }
    for (int t = tid; t < 128; t += 256)          // osb cols 60..63 := 0
        ((unsigned int*)osb)[(t >> 1) * 36 + 30 + (t & 1)] = 0u;
    for (int t = tid; t < 1296; t += 256) {       // vall pad rows (d=10..15) := 0
        int r36 = t / 36, cdw = t - r36 * 36;
        int h = r36 / 6, d = 10 + (r36 - h * 6);
        ((unsigned int*)vall)[(h * 16 + d) * 36 + cdw] = 0u;
    }
    __syncthreads();

    // ---- phase 1: QKV = xb @ qkv_w  (wave w owns m-tile w) -----------------
    {
        Frag a0, a1;
        a0.i4 = *(const int4*)&uni[(wid * 16 + l15) * 72 + g * 8];
        a1.i4 = *(const int4*)&uni[(wid * 16 + l15) * 72 + 32 + g * 8];
        const int4* wf = (const int4*)ws;
        #pragma unroll 4
        for (int n = 0; n < 12; ++n) {
            Frag b0, b1;
            b0.i4 = wf[(n * 2 + 0) * 64 + lane];
            b1.i4 = wf[(n * 2 + 1) * 64 + lane];
            f32x4 acc = {0.f, 0.f, 0.f, 0.f};
            acc = MFMA(a0.b8, b0.b8, acc);
            acc = MFMA(a1.b8, b1.b8, acc);
            int c = n * 16 + l15;
            if (c < 180) {
                int which = (c >= 120) ? 2 : ((c >= 60) ? 1 : 0);
                int cc = c - which * 60;
                int h  = (cc * 205) >> 11;       // cc/10 for cc<64
                int d  = cc - h * 10;
                #pragma unroll
                for (int j = 0; j < 4; ++j) {
                    int tok = wid * 16 + g * 4 + j;
                    unsigned short bv = f2bf(acc[j]);
                    if (which == 0)      qall[tok * 104 + h * 16 + d] = bv;
                    else if (which == 1) kall[tok * 104 + h * 16 + d] = bv;
                    else                 vall[(h * 16 + d) * 72 + tok] = bv;
                }
            }
        }
    }
    __syncthreads();

    // ---- phase 2: attention, 6 units of (head, m-tile) per wave, 0 barriers -
    unsigned short* pslab = &uni[wid * 16 * 72];
    #pragma unroll 1
    for (int u = 0; u < 6; ++u) {
        int hm = wid * 6 + u;       // 0..23
        int h  = hm >> 2;
        int m  = hm & 3;

        // S = q k^T  (K=32 MFMA, k>=10 zero-masked in registers)
        int khalf = (g >= 1) ? 8 : 0;
        Frag qa;
        qa.i4 = *(const int4*)&qall[(m * 16 + l15) * 104 + h * 16 + khalf];
        qa.i4.x = (g <= 1) ? qa.i4.x : 0;
        qa.i4.y = (g == 0) ? qa.i4.y : 0;
        qa.i4.z = (g == 0) ? qa.i4.z : 0;
        qa.i4.w = (g == 0) ? qa.i4.w : 0;

        f32x4 sacc[4];
        #pragma unroll
        for (int n = 0; n < 4; ++n) {
            Frag kb;
            kb.i4 = *(const int4*)&kall[(n * 16 + l15) * 104 + h * 16 + khalf];
            kb.i4.x = (g <= 1) ? kb.i4.x : 0;
            kb.i4.y = (g == 0) ? kb.i4.y : 0;
            kb.i4.z = (g == 0) ? kb.i4.z : 0;
            kb.i4.w = (g == 0) ? kb.i4.w : 0;
            f32x4 z = {0.f, 0.f, 0.f, 0.f};
            sacc[n] = MFMA(qa.b8, kb.b8, z);
        }

        // bias + mask + scale, then in-register row softmax (rows i=m*16+g*4+j)
        float p[4][4];
        #pragma unroll
        for (int j = 0; j < 4; ++j) {
            int i  = m * 16 + g * 4 + j;
            int yi = i >> 3, xi = i & 7;
            int pi = regionOf(wh * 8 + yi) * 3 + regionOf(ww * 8 + xi);
            #pragma unroll
            for (int n = 0; n < 4; ++n) {
                int jt = n * 16 + l15;
                int yj = jt >> 3, xj = jt & 7;
                int pj = regionOf(wh * 8 + yj) * 3 + regionOf(ww * 8 + xj);
                int ridx = (yi - yj + 7) * 15 + (xi - xj + 7);
                float v = fmaf(sacc[n][j], 0.31622776601683794f, biasm[ridx * 6 + h]);
                if (pi != pj) v -= 100.0f;
                p[j][n] = v;
            }
        }
        float rinv[4];
        #pragma unroll
        for (int j = 0; j < 4; ++j) {
            float mx = fmaxf(fmaxf(p[j][0], p[j][1]), fmaxf(p[j][2], p[j][3]));
            mx = fmaxf(mx, __shfl_xor(mx, 1));
            mx = fmaxf(mx, __shfl_xor(mx, 2));
            mx = fmaxf(mx, __shfl_xor(mx, 4));
            mx = fmaxf(mx, __shfl_xor(mx, 8));
            float s = 0.f;
            #pragma unroll
            for (int n = 0; n < 4; ++n) { p[j][n] = __expf(p[j][n] - mx); s += p[j][n]; }
            s += __shfl_xor(s, 1);
            s += __shfl_xor(s, 2);
            s += __shfl_xor(s, 4);
            s += __shfl_xor(s, 8);
            rinv[j] = 1.0f / s;
        }
        // write unnormalized P (bf16) to this wave's private slab
        #pragma unroll
        for (int j = 0; j < 4; ++j)
            #pragma unroll
            for (int n = 0; n < 4; ++n)
                pslab[(g * 4 + j) * 72 + n * 16 + l15] = f2bf(p[j][n]);

        // PV: A = P slab rows, B = vall head h (same-wave LDS dep, no barrier)
        f32x4 pv = {0.f, 0.f, 0.f, 0.f};
        #pragma unroll
        for (int ks = 0; ks < 2; ++ks) {
            Frag pa, vb;
            pa.i4 = *(const int4*)&pslab[l15 * 72 + ks * 32 + g * 8];
            vb.i4 = *(const int4*)&vall[(h * 16 + l15) * 72 + ks * 32 + g * 8];
            pv = MFMA(pa.b8, vb.b8, pv);
        }
        if (l15 < 10) {
            #pragma unroll
            for (int j = 0; j < 4; ++j)
                osb[(m * 16 + g * 4 + j) * 72 + h * 10 + l15] = f2bf(pv[j] * rinv[j]);
        }
    }
    __syncthreads();

    // ---- phase 3: proj = osb @ proj_w + pb, store with reverse shift -------
    {
        Frag a0, a1;
        a0.i4 = *(const int4*)&osb[(wid * 16 + l15) * 72 + g * 8];
        a1.i4 = *(const int4*)&osb[(wid * 16 + l15) * 72 + 32 + g * 8];
        const int4* wf = (const int4*)(ws + 24576);
        #pragma unroll
        for (int n = 0; n < 4; ++n) {
            Frag b0, b1;
            b0.i4 = wf[(n * 2 + 0) * 64 + lane];
            b1.i4 = wf[(n * 2 + 1) * 64 + lane];
            f32x4 acc = {0.f, 0.f, 0.f, 0.f};
            acc = MFMA(a0.b8, b0.b8, acc);
            acc = MFMA(a1.b8, b1.b8, acc);
            int c = n * 16 + l15;
            if (c < 60) {
                float bv = pbias[c];
                #pragma unroll
                for (int j = 0; j < 4; ++j) {
                    int tok = wid * 16 + g * 4 + j;
                    int yi = tok >> 3, xi = tok & 7;
                    int sh = wh * 8 + yi + 4; if (sh >= IMG) sh -= IMG;
                    int sw = ww * 8 + xi + 4; if (sw >= IMG) sw -= IMG;
                    out[((b * IMG + sh) * IMG + sw) * CDIM + c] = acc[j] + bv;
                }
            }
        }
    }
}

extern "C" void kernel_launch(void* const* d_in, const int* in_sizes, int n_in,
                              void* d_out, int out_size, void* d_ws, size_t ws_size,
                              hipStream_t stream) {
    const float* img  = (const float*)d_in[0];
    const float* qw   = (const float*)d_in[1];
    const float* bias = (const float*)d_in[2];
    const float* pw   = (const float*)d_in[3];
    const float* pb   = (const float*)d_in[4];
    float* out = (float*)d_out;

    swin_prep<<<8, 256, 0, stream>>>(qw, pw, (unsigned char*)d_ws);
    swin_mfma<<<4 * WNUM, 256, 0, stream>>>(img, bias, pb,
                                            (const unsigned char*)d_ws, out);
}

// Round 3
// 224.829 us; speedup vs baseline: 7.2667x; 2.1787x over previous
//
#include <hip/hip_runtime.h>
#include <hip/hip_bf16.h>

#define IMG    384
#define CDIM   60
#define NWIN   48
#define WNUM   (NWIN * NWIN)   // 2304

typedef short  bf16x8 __attribute__((ext_vector_type(8)));
typedef float  f32x4  __attribute__((ext_vector_type(4)));
union Frag { int4 i4; bf16x8 b8; };

#define MFMA(a, b, c) __builtin_amdgcn_mfma_f32_16x16x32_bf16((a), (b), (c), 0, 0, 0)

#define WS_QKVF  0        // 18 mtiles x 2 ks x 64 lanes x 16B = 36864
#define WS_PROJF 36864    // 4 x 2 x 64 x 16B = 8192
#define WS_BIAS  45056    // [6][64 i][64 j] bf16 (pre-scaled by log2e) = 49152

#define SCALE_L2E (0.31622776601683794f * 1.4426950408889634f)  // 1/sqrt(10)*log2(e)
#define MASK_L2E  144.26950408889634f                            // 100*log2(e)

__device__ __forceinline__ unsigned short f2bf(float f) {
    unsigned int u = __float_as_uint(f);
    unsigned int r = u + 0x7fffu + ((u >> 16) & 1u);
    return (unsigned short)(r >> 16);
}
__device__ __forceinline__ unsigned int pk2bf(float a, float b) {
    union { __hip_bfloat162 h; unsigned int u; } c;
    c.h = __float22bfloat162_rn(float2{a, b});
    return c.u;
}
__device__ __forceinline__ int regionOf(int x) {
    return (x < IMG - 8) ? 0 : ((x < IMG - 4) ? 1 : 2);
}
// XOR-swizzled q/k address (stride 96 shorts = 192B rows); both reads & writes use it
__device__ __forceinline__ unsigned short* qk_addr(unsigned short* buf, int tok, int byteoff) {
    int byte = (tok * 192 + byteoff) ^ ((tok & 7) << 4);
    return (unsigned short*)((char*)buf + byte);
}

// ---------------------------------------------------------------------------
// Prep: weight A-frags + prescaled bf16 bias table into d_ws
// ---------------------------------------------------------------------------
__global__ void swin_prep(const float* __restrict__ qw,    // [60][180]
                          const float* __restrict__ pw,    // [60][60]
                          const float* __restrict__ bias,  // [225][6]
                          unsigned char* __restrict__ ws)
{
    int t = blockIdx.x * 256 + threadIdx.x;
    if (t < 2304) {                       // QKV^T A-frags, padded M=288 rows
        int lane = t & 63, fq = t >> 6;   // fq 0..35
        int mt = fq >> 1, ks = fq & 1;
        int h = mt / 3, type = mt - h * 3;   // rows: h*48 + type*16 + d
        int d = lane & 15;
        int g8 = lane >> 4;
        unsigned short v8[8];
        #pragma unroll
        for (int jj = 0; jj < 8; ++jj) {
            int c = ks * 32 + g8 * 8 + jj;
            float v = (d < 10 && c < 60) ? qw[c * 180 + type * 60 + h * 10 + d] : 0.f;
            v8[jj] = f2bf(v);
        }
        int4 p;
        p.x = v8[0] | (v8[1] << 16);  p.y = v8[2] | (v8[3] << 16);
        p.z = v8[4] | (v8[5] << 16);  p.w = v8[6] | (v8[7] << 16);
        *(int4*)(ws + WS_QKVF + t * 16) = p;
    } else if (t < 2816) {                // proj^T A-frags, padded M=64 rows
        int t2 = t - 2304;
        int lane = t2 & 63, fq = t2 >> 6; // fq 0..7
        int m = fq >> 1, ks = fq & 1;
        int c = m * 16 + (lane & 15);
        int g8 = lane >> 4;
        unsigned short v8[8];
        #pragma unroll
        for (int jj = 0; jj < 8; ++jj) {
            int cc = ks * 32 + g8 * 8 + jj;
            float v = (c < 60 && cc < 60) ? pw[cc * 60 + c] : 0.f;
            v8[jj] = f2bf(v);
        }
        int4 p;
        p.x = v8[0] | (v8[1] << 16);  p.y = v8[2] | (v8[3] << 16);
        p.z = v8[4] | (v8[5] << 16);  p.w = v8[6] | (v8[7] << 16);
        *(int4*)(ws + WS_PROJF + t2 * 16) = p;
    } else if (t < 2816 + 12288) {        // bias table [6][i 64][j 64] bf16*log2e
        int idx = t - 2816;
        int h = idx >> 11, r = idx & 2047;
        int i = r >> 5, j0 = (r & 31) * 2;
        int yi = i >> 3, xi = i & 7;
        unsigned int pk = 0;
        #pragma unroll
        for (int jj = 0; jj < 2; ++jj) {
            int j = j0 + jj;
            int yj = j >> 3, xj = j & 7;
            int ridx = (yi - yj + 7) * 15 + (xi - xj + 7);
            float v = bias[ridx * 6 + h] * 1.4426950408889634f;
            pk |= ((unsigned int)f2bf(v)) << (16 * jj);
        }
        *(unsigned int*)(ws + WS_BIAS + (h * 4096 + i * 64 + j0) * 2) = pk;
    }
}

// ---------------------------------------------------------------------------
// Main fused kernel: one 256-thread block per window, 3 barriers, 52.5 KB LDS
// ---------------------------------------------------------------------------
__global__ __launch_bounds__(256, 3)
void swin_mfma(const float* __restrict__ img,
               const float* __restrict__ pbias,   // [60]
               const unsigned char* __restrict__ ws,
               float* __restrict__ out)
{
    __shared__ unsigned short uni [64 * 72];  // xb [tok][72] U P-slabs [4][16][72]
    __shared__ unsigned short qall[64 * 96];  // [tok][h*16+d] swizzled, pads = 0
    __shared__ unsigned short kall[64 * 96];
    __shared__ unsigned short vall[66 * 72];  // [h*11 + d][tok]; row d=10 = ones
    __shared__ unsigned short osb [64 * 72];  // [tok][h*10+d]; cols 60..63 = 0

    const int tid  = threadIdx.x;
    const int lane = tid & 63;
    const int wid  = __builtin_amdgcn_readfirstlane(tid >> 6);
    const int l15  = lane & 15;
    const int g    = lane >> 4;

    const int bid = blockIdx.x;
    const int b   = bid / WNUM;
    const int wi  = bid - b * WNUM;
    const int wh  = wi / NWIN;
    const int ww  = wi - wh * NWIN;
    const bool boundary = (wh == NWIN - 1) || (ww == NWIN - 1);

    // ---- phase 0: load window (shift folded), float4 -> bf16 b64 writes ----
    #pragma unroll
    for (int it = 0; it < 4; ++it) {
        int idx = tid + it * 256;            // 960 float4s total
        if (idx < 960) {
            int tok = idx / 15, cg = idx - tok * 15;
            int yi = tok >> 3, xi = tok & 7;
            int sh = wh * 8 + yi + 4; if (sh >= IMG) sh -= IMG;
            int sw = ww * 8 + xi + 4; if (sw >= IMG) sw -= IMG;
            float4 v = *(const float4*)&img[((b * IMG + sh) * IMG + sw) * CDIM + cg * 4];
            int2 pk = make_int2(pk2bf(v.x, v.y), pk2bf(v.z, v.w));
            *(int2*)&uni[tok * 72 + cg * 4] = pk;
        }
    }
    if (tid < 128) {                          // uni & osb cols 60..63 := 0
        int tok = tid >> 1, half = tid & 1;
        ((unsigned int*)uni)[tok * 36 + 30 + half] = 0u;
        ((unsigned int*)osb)[tok * 36 + 30 + half] = 0u;
    }
    if (tid < 216) {                          // vall ones-row (d=10) per head
        int h = tid / 36, s = tid - h * 36;
        ((unsigned int*)vall)[(h * 11 + 10) * 36 + s] = 0x3F803F80u;
    }
    __syncthreads();

    // ---- phase 1: QKV^T = Wpad^T . X^T  (18 mtiles over 4 waves) -----------
    {
        Frag xb[4][2];
        #pragma unroll
        for (int n = 0; n < 4; ++n)
            #pragma unroll
            for (int ks = 0; ks < 2; ++ks)
                xb[n][ks].i4 = *(const int4*)&uni[(n * 16 + l15) * 72 + ks * 32 + g * 8];

        const int4* wsq = (const int4*)(ws + WS_QKVF);
        for (int mt = wid; mt < 18; mt += 4) {
            int h = mt / 3, type = mt - h * 3;
            Frag a0, a1;
            a0.i4 = wsq[(mt * 2 + 0) * 64 + lane];
            a1.i4 = wsq[(mt * 2 + 1) * 64 + lane];
            #pragma unroll
            for (int n = 0; n < 4; ++n) {
                f32x4 acc = {0.f, 0.f, 0.f, 0.f};
                acc = MFMA(a0.b8, xb[n][0].b8, acc);
                acc = MFMA(a1.b8, xb[n][1].b8, acc);
                int tok = n * 16 + l15;
                if (type < 2) {               // q/k: 4 consecutive d -> b64
                    int2 pk = make_int2(pk2bf(acc[0], acc[1]), pk2bf(acc[2], acc[3]));
                    *(int2*)qk_addr(type == 0 ? qall : kall, tok, h * 32 + g * 8) = pk;
                } else {                      // v: [d][tok] scalar, d<10 only
                    #pragma unroll
                    for (int jj = 0; jj < 4; ++jj) {
                        int d = g * 4 + jj;
                        if (d < 10) vall[(h * 11 + d) * 72 + tok] = f2bf(acc[jj]);
                    }
                }
            }
        }
    }
    __syncthreads();

    // ---- phase 2: attention, S^T form, 6 (h,m) units per wave, no barriers -
    unsigned short* pslab = &uni[wid * 16 * 72];
    const unsigned short* bws = (const unsigned short*)(ws + WS_BIAS);
    const int khalf = (g & 1) * 16;           // byte offset of k-half within head

    #pragma unroll 1
    for (int u = 0; u < 6; ++u) {
        int hm = wid * 6 + u;
        int h  = hm >> 2;
        int m  = hm & 3;

        Frag qa;
        qa.i4 = *(const int4*)qk_addr(qall, m * 16 + l15, h * 32 + khalf);
        if (g >= 2) qa.i4 = int4{0, 0, 0, 0};

        f32x4 sacc[4];
        #pragma unroll
        for (int n = 0; n < 4; ++n) {
            Frag kb;
            kb.i4 = *(const int4*)qk_addr(kall, n * 16 + l15, h * 32 + khalf);
            if (g >= 2) kb.i4 = int4{0, 0, 0, 0};
            f32x4 zz = {0.f, 0.f, 0.f, 0.f};
            sacc[n] = MFMA(kb.b8, qa.b8, zz);    // S^T: row=j, col=i
        }

        // bias (prescaled) + scale; lane holds column i = m*16+l15, 16 j's
        const unsigned short* bp = bws + h * 4096 + (m * 16 + l15) * 64;
        float p[4][4];
        #pragma unroll
        for (int n = 0; n < 4; ++n) {
            ushort4 bb = *(const ushort4*)(bp + n * 16 + g * 4);
            p[n][0] = fmaf(sacc[n][0], SCALE_L2E, __uint_as_float(((unsigned)bb.x) << 16));
            p[n][1] = fmaf(sacc[n][1], SCALE_L2E, __uint_as_float(((unsigned)bb.y) << 16));
            p[n][2] = fmaf(sacc[n][2], SCALE_L2E, __uint_as_float(((unsigned)bb.z) << 16));
            p[n][3] = fmaf(sacc[n][3], SCALE_L2E, __uint_as_float(((unsigned)bb.w) << 16));
        }
        if (boundary) {
            int i = m * 16 + l15;
            int pi = regionOf(wh * 8 + (i >> 3)) * 3 + regionOf(ww * 8 + (i & 7));
            #pragma unroll
            for (int n = 0; n < 4; ++n)
                #pragma unroll
                for (int jj = 0; jj < 4; ++jj) {
                    int j = n * 16 + g * 4 + jj;
                    int pj = regionOf(wh * 8 + (j >> 3)) * 3 + regionOf(ww * 8 + (j & 7));
                    if (pi != pj) p[n][jj] -= MASK_L2E;
                }
        }

        // column max: 15 local + 2 shfls
        float mx = p[0][0];
        #pragma unroll
        for (int n = 0; n < 4; ++n)
            #pragma unroll
            for (int jj = 0; jj < 4; ++jj) mx = fmaxf(mx, p[n][jj]);
        mx = fmaxf(mx, __shfl_xor(mx, 16));
        mx = fmaxf(mx, __shfl_xor(mx, 32));

        // exp2 + pack P^T rows into [i][j] slab (b64 per n)
        #pragma unroll
        for (int n = 0; n < 4; ++n) {
            float e0 = __builtin_exp2f(p[n][0] - mx);
            float e1 = __builtin_exp2f(p[n][1] - mx);
            float e2 = __builtin_exp2f(p[n][2] - mx);
            float e3 = __builtin_exp2f(p[n][3] - mx);
            *(int2*)&pslab[l15 * 72 + n * 16 + g * 4] =
                make_int2(pk2bf(e0, e1), pk2bf(e2, e3));
        }

        // O^T = V^T . P^T  (ones-row gives denominator in C row d=10)
        int vrow = (l15 < 10) ? l15 : 10;
        f32x4 pv = {0.f, 0.f, 0.f, 0.f};
        #pragma unroll
        for (int ks = 0; ks < 2; ++ks) {
            Frag va, pb2;
            va.i4  = *(const int4*)&vall[(h * 11 + vrow) * 72 + ks * 32 + g * 8];
            pb2.i4 = *(const int4*)&pslab[l15 * 72 + ks * 32 + g * 8];
            pv = MFMA(va.b8, pb2.b8, pv);
        }
        float denom = __shfl(pv[2], 32 + l15);   // C row 10, col i
        float rinv  = __builtin_amdgcn_rcpf(denom);

        int base = (m * 16 + l15) * 72 + h * 10;
        if (g == 0) {
            ((unsigned int*)osb)[(base + 0) >> 1] = pk2bf(pv[0] * rinv, pv[1] * rinv);
            ((unsigned int*)osb)[(base + 2) >> 1] = pk2bf(pv[2] * rinv, pv[3] * rinv);
        } else if (g == 1) {
            ((unsigned int*)osb)[(base + 4) >> 1] = pk2bf(pv[0] * rinv, pv[1] * rinv);
            ((unsigned int*)osb)[(base + 6) >> 1] = pk2bf(pv[2] * rinv, pv[3] * rinv);
        } else if (g == 2) {
            ((unsigned int*)osb)[(base + 8) >> 1] = pk2bf(pv[0] * rinv, pv[1] * rinv);
        }
    }
    __syncthreads();

    // ---- phase 3: Y^T = Wp^T . O^T, float4 stores with reverse shift -------
    {
        const int4* wsp = (const int4*)(ws + WS_PROJF);
        Frag a0, a1;
        a0.i4 = wsp[(wid * 2 + 0) * 64 + lane];
        a1.i4 = wsp[(wid * 2 + 1) * 64 + lane];
        int c0 = wid * 16 + g * 4;
        float4 pbv = (c0 < 60) ? *(const float4*)&pbias[c0] : float4{0.f, 0.f, 0.f, 0.f};
        #pragma unroll
        for (int n = 0; n < 4; ++n) {
            Frag b0, b1;
            b0.i4 = *(const int4*)&osb[(n * 16 + l15) * 72 + g * 8];
            b1.i4 = *(const int4*)&osb[(n * 16 + l15) * 72 + 32 + g * 8];
            f32x4 acc = {0.f, 0.f, 0.f, 0.f};
            acc = MFMA(a0.b8, b0.b8, acc);
            acc = MFMA(a1.b8, b1.b8, acc);
            if (c0 < 60) {
                int tok = n * 16 + l15;
                int yi = tok >> 3, xi = tok & 7;
                int sh = wh * 8 + yi + 4; if (sh >= IMG) sh -= IMG;
                int sw = ww * 8 + xi + 4; if (sw >= IMG) sw -= IMG;
                float4 o = {acc[0] + pbv.x, acc[1] + pbv.y, acc[2] + pbv.z, acc[3] + pbv.w};
                *(float4*)&out[((b * IMG + sh) * IMG + sw) * CDIM + c0] = o;
            }
        }
    }
}

extern "C" void kernel_launch(void* const* d_in, const int* in_sizes, int n_in,
                              void* d_out, int out_size, void* d_ws, size_t ws_size,
                              hipStream_t stream) {
    const float* img  = (const float*)d_in[0];
    const float* qw   = (const float*)d_in[1];
    const float* bias = (const float*)d_in[2];
    const float* pw   = (const float*)d_in[3];
    const float* pb   = (const float*)d_in[4];
    float* out = (float*)d_out;

    swin_prep<<<59, 256, 0, stream>>>(qw, pw, bias, (unsigned char*)d_ws);
    swin_mfma<<<4 * WNUM, 256, 0, stream>>>(img, pb,
                                            (const unsigned char*)d_ws, out);
}

// Round 4
// 190.934 us; speedup vs baseline: 8.5566x; 1.1775x over previous
//
#include <hip/hip_runtime.h>
#include <hip/hip_bf16.h>

#define IMG    384
#define CDIM   60
#define NWIN   48
#define WNUM   (NWIN * NWIN)   // 2304

typedef short  bf16x8 __attribute__((ext_vector_type(8)));
typedef float  f32x4  __attribute__((ext_vector_type(4)));
union Frag { int4 i4; bf16x8 b8; };

#define MFMA(a, b, c) __builtin_amdgcn_mfma_f32_16x16x32_bf16((a), (b), (c), 0, 0, 0)

// d_ws layout
#define WS_QKVF  0        // 12 qk mtiles x 2 ks x 1KB = 24576
#define WS_VF    24576    // 6 v mtiles x 2 ks x 1KB   = 12288
#define WS_PROJF 36864    // 4 x 2 x 1KB               = 8192
#define WS_BIASF 45056    // [6][64][64] f32 (prescaled by log2e) = 98304

#define SCALE_L2E (0.31622776601683794f * 1.4426950408889634f)  // 1/sqrt(10)*log2(e)
#define MASK_L2E  144.26950408889634f                            // 100*log2(e)
#define LOG2E     1.4426950408889634f

__device__ __forceinline__ unsigned short f2bf(float f) {
    unsigned int u = __float_as_uint(f);
    unsigned int r = u + 0x7fffu + ((u >> 16) & 1u);
    return (unsigned short)(r >> 16);
}
__device__ __forceinline__ unsigned int pk2bf(float a, float b) {
    union { __hip_bfloat162 h; unsigned int u; } c;
    c.h = __float22bfloat162_rn(float2{a, b});
    return c.u;
}
__device__ __forceinline__ int regionOf(int x) {
    return (x < IMG - 8) ? 0 : ((x < IMG - 4) ? 1 : 2);
}
// XOR-swizzled q/k byte address (rows = 192B); writes & reads use identical formula
__device__ __forceinline__ int qk_byte(int tok, int byteoff) {
    return (tok * 192 + byteoff) ^ ((tok & 7) << 4);
}

// ---------------------------------------------------------------------------
// Prep: weight A-frags (bf16) + f32 bias table (prescaled by log2e) in d_ws
// ---------------------------------------------------------------------------
__global__ void swin_prep(const float* __restrict__ qw,    // [60][180]
                          const float* __restrict__ pw,    // [60][60]
                          const float* __restrict__ bias,  // [225][6]
                          unsigned char* __restrict__ ws)
{
    int t = blockIdx.x * 256 + threadIdx.x;
    if (t < 1536) {                        // q/k A-frags: mt = h*2+type, f = mt*2+ks
        int lane = t & 63, f = t >> 6;
        int mt = f >> 1, ks = f & 1;
        int h = mt >> 1, type = mt & 1;
        int d = lane & 15, g8 = lane >> 4;
        unsigned short v8[8];
        #pragma unroll
        for (int jj = 0; jj < 8; ++jj) {
            int c = ks * 32 + g8 * 8 + jj;
            v8[jj] = f2bf((d < 10 && c < 60) ? qw[c * 180 + type * 60 + h * 10 + d] : 0.f);
        }
        int4 p;
        p.x = v8[0] | (v8[1] << 16);  p.y = v8[2] | (v8[3] << 16);
        p.z = v8[4] | (v8[5] << 16);  p.w = v8[6] | (v8[7] << 16);
        *(int4*)(ws + WS_QKVF + t * 16) = p;
    } else if (t < 2304) {                 // v A-frags: f = h*2+ks
        int t2 = t - 1536;
        int lane = t2 & 63, f = t2 >> 6;
        int h = f >> 1, ks = f & 1;
        int d = lane & 15, g8 = lane >> 4;
        unsigned short v8[8];
        #pragma unroll
        for (int jj = 0; jj < 8; ++jj) {
            int c = ks * 32 + g8 * 8 + jj;
            v8[jj] = f2bf((d < 10 && c < 60) ? qw[c * 180 + 120 + h * 10 + d] : 0.f);
        }
        int4 p;
        p.x = v8[0] | (v8[1] << 16);  p.y = v8[2] | (v8[3] << 16);
        p.z = v8[4] | (v8[5] << 16);  p.w = v8[6] | (v8[7] << 16);
        *(int4*)(ws + WS_VF + t2 * 16) = p;
    } else if (t < 2816) {                 // proj^T A-frags
        int t2 = t - 2304;
        int lane = t2 & 63, fq = t2 >> 6;
        int m = fq >> 1, ks = fq & 1;
        int c = m * 16 + (lane & 15);
        int g8 = lane >> 4;
        unsigned short v8[8];
        #pragma unroll
        for (int jj = 0; jj < 8; ++jj) {
            int cc = ks * 32 + g8 * 8 + jj;
            v8[jj] = f2bf((c < 60 && cc < 60) ? pw[cc * 60 + c] : 0.f);
        }
        int4 p;
        p.x = v8[0] | (v8[1] << 16);  p.y = v8[2] | (v8[3] << 16);
        p.z = v8[4] | (v8[5] << 16);  p.w = v8[6] | (v8[7] << 16);
        *(int4*)(ws + WS_PROJF + t2 * 16) = p;
    } else if (t < 2816 + 24576) {         // bias f32 table [6][i 64][j 64] * log2e
        int idx = t - 2816;
        int h = idx >> 12, r = idx & 4095;
        int i = r >> 6, j = r & 63;
        int yi = i >> 3, xi = i & 7, yj = j >> 3, xj = j & 7;
        int ridx = (yi - yj + 7) * 15 + (xi - xj + 7);
        ((float*)(ws + WS_BIASF))[h * 4096 + i * 64 + j] = bias[ridx * 6 + h] * LOG2E;
    }
}

// ---------------------------------------------------------------------------
// Main fused kernel: one 256-thread block per window, 3 barriers, 52.7 KB LDS
// ---------------------------------------------------------------------------
__global__ __launch_bounds__(256, 3)
void swin_mfma(const float* __restrict__ img,
               const float* __restrict__ pbias,   // [60]
               const unsigned char* __restrict__ ws,
               float* __restrict__ out)
{
    __shared__ unsigned short uni [64 * 72];  // xb [tok][72] U P-slabs [4][16][72]
    __shared__ unsigned short qall[64 * 96];  // [tok][h*16+d] XOR-swizzled
    __shared__ unsigned short kall[64 * 96];
    __shared__ unsigned short vall[66 * 72];  // [h*11+d][tok]; row d=10 = ones
    __shared__ unsigned short osb [64 * 72];  // [tok][h*10+d]; cols 60..63 = 0
    __shared__ __align__(16) int zfrag[4];    // 16B zero page

    const int tid  = threadIdx.x;
    const int lane = tid & 63;
    const int wid  = __builtin_amdgcn_readfirstlane(tid >> 6);
    const int l15  = lane & 15;
    const int g    = lane >> 4;
    const bool zg  = (lane >= 32);            // g >= 2
    const int dl   = (32 + l15) << 2;         // bpermute lane for denominator

    const int bid = blockIdx.x;
    const int b   = bid / WNUM;
    const int wi  = bid - b * WNUM;
    const int wh  = wi / NWIN;
    const int ww  = wi - wh * NWIN;
    const bool boundary = (wh == NWIN - 1) || (ww == NWIN - 1);

    // ---- phase 0: load window (shift folded), token=lane, chunk=wid --------
    {
        int tok = lane;
        int yi = tok >> 3, xi = tok & 7;
        int sh = wh * 8 + yi + 4; if (sh >= IMG) sh -= IMG;
        int sw = ww * 8 + xi + 4; if (sw >= IMG) sw -= IMG;
        const float* src = img + ((size_t)(b * IMG + sh) * IMG + sw) * CDIM;
        #pragma unroll
        for (int it = 0; it < 4; ++it) {
            int cg = wid + it * 4;
            if (cg < 15) {
                float4 v = *(const float4*)(src + cg * 4);
                *(int2*)&uni[tok * 72 + cg * 4] =
                    make_int2(pk2bf(v.x, v.y), pk2bf(v.z, v.w));
            } else {
                *(int2*)&uni[tok * 72 + 60] = make_int2(0, 0);  // pad cols 60..63
            }
        }
    }
    if (tid < 128) {                           // osb cols 60..63 := 0
        int row = tid >> 1, half = tid & 1;
        *(unsigned int*)&osb[row * 72 + 60 + half * 2] = 0u;
    }
    if (tid < 192) {                           // vall ones-row (d=10) per head
        int h = tid >> 5, s = tid & 31;
        ((unsigned int*)vall)[((h * 11 + 10) * 72 >> 1) + s] = 0x3F803F80u;
    }
    if (tid < 4) zfrag[tid] = 0;
    __syncthreads();

    // ---- phase 1: QKV^T (12 q/k mtiles: 3/wave; 6 v mtiles: wave<2 gets 2) -
    {
        Frag xb[4][2];
        #pragma unroll
        for (int n = 0; n < 4; ++n)
            #pragma unroll
            for (int ks = 0; ks < 2; ++ks)
                xb[n][ks].i4 = *(const int4*)&uni[(n * 16 + l15) * 72 + ks * 32 + g * 8];

        const int4* wsq = (const int4*)(ws + WS_QKVF);
        #pragma unroll
        for (int kk = 0; kk < 3; ++kk) {
            int mt = wid + kk * 4;             // uniform
            int h = mt >> 1, type = mt & 1;
            Frag a0, a1;
            a0.i4 = wsq[(mt * 2 + 0) * 64 + lane];
            a1.i4 = wsq[(mt * 2 + 1) * 64 + lane];
            unsigned short* dst = type ? kall : qall;
            #pragma unroll
            for (int n = 0; n < 4; ++n) {
                f32x4 acc = {0.f, 0.f, 0.f, 0.f};
                acc = MFMA(a0.b8, xb[n][0].b8, acc);
                acc = MFMA(a1.b8, xb[n][1].b8, acc);
                int tok = n * 16 + l15;
                *(int2*)((char*)dst + qk_byte(tok, h * 32 + g * 8)) =
                    make_int2(pk2bf(acc[0], acc[1]), pk2bf(acc[2], acc[3]));
            }
        }
        const int4* wsv = (const int4*)(ws + WS_VF);
        int nv = (wid < 2) ? 2 : 1;
        #pragma unroll 1
        for (int kk = 0; kk < nv; ++kk) {
            int hv = wid + kk * 4;             // covers h 0..5
            Frag a0, a1;
            a0.i4 = wsv[(hv * 2 + 0) * 64 + lane];
            a1.i4 = wsv[(hv * 2 + 1) * 64 + lane];
            #pragma unroll
            for (int n = 0; n < 4; ++n) {
                f32x4 acc = {0.f, 0.f, 0.f, 0.f};
                acc = MFMA(a0.b8, xb[n][0].b8, acc);
                acc = MFMA(a1.b8, xb[n][1].b8, acc);
                int tok = n * 16 + l15;
                #pragma unroll
                for (int jj = 0; jj < 4; ++jj) {
                    int d = g * 4 + jj;
                    if (d < 10) vall[(hv * 11 + d) * 72 + tok] = f2bf(acc[jj]);
                }
            }
        }
    }
    __syncthreads();

    // ---- phase 2: attention, h-grouped (frag hoisting), no-max softmax -----
    unsigned short* pslab = &uni[wid * 16 * 72];
    const float* biasf = (const float*)(ws + WS_BIASF);

    int h  = wid + (wid >> 1);                 // first head of this wave
    int m0 = (wid & 1) * 2;
    int mc = 4 - (wid & 1) * 2;
    #pragma unroll 1
    for (int grp = 0; grp < 2; ++grp) {
        const int koff = h * 32 + (g & 1) * 16;
        // hoisted K-fragments for this head (zero-page for k>=16 half)
        Frag kb[4];
        #pragma unroll
        for (int n = 0; n < 4; ++n) {
            int tok = n * 16 + l15;
            const int4* pa = zg ? (const int4*)zfrag
                                : (const int4*)((const char*)kall + qk_byte(tok, koff));
            kb[n].i4 = *pa;
        }
        // hoisted V-fragments (row d=10 = ones gives denominator)
        int vrow = (l15 < 10) ? l15 : 10;
        Frag va[2];
        #pragma unroll
        for (int ks = 0; ks < 2; ++ks)
            va[ks].i4 = *(const int4*)&vall[(h * 11 + vrow) * 72 + ks * 32 + g * 8];

        #pragma unroll 1
        for (int m = m0; m < m0 + mc; ++m) {
            int i_tok = m * 16 + l15;
            Frag qa;
            {
                const int4* pa = zg ? (const int4*)zfrag
                                    : (const int4*)((const char*)qall + qk_byte(i_tok, koff));
                qa.i4 = *pa;
            }
            f32x4 sacc[4];
            #pragma unroll
            for (int n = 0; n < 4; ++n) {
                f32x4 zz = {0.f, 0.f, 0.f, 0.f};
                sacc[n] = MFMA(kb[n].b8, qa.b8, zz);   // S^T: col=i, rows=j
            }
            // bias (f32, prescaled by log2e) + scale
            const float* bp = biasf + ((h << 6) + i_tok) * 64;
            float p[4][4];
            #pragma unroll
            for (int n = 0; n < 4; ++n) {
                float4 bb = *(const float4*)(bp + n * 16 + (g << 2));
                p[n][0] = fmaf(sacc[n][0], SCALE_L2E, bb.x);
                p[n][1] = fmaf(sacc[n][1], SCALE_L2E, bb.y);
                p[n][2] = fmaf(sacc[n][2], SCALE_L2E, bb.z);
                p[n][3] = fmaf(sacc[n][3], SCALE_L2E, bb.w);
            }
            if (boundary) {
                int pi = regionOf(wh * 8 + (i_tok >> 3)) * 3 + regionOf(ww * 8 + (i_tok & 7));
                #pragma unroll
                for (int n = 0; n < 4; ++n)
                    #pragma unroll
                    for (int jj = 0; jj < 4; ++jj) {
                        int j = n * 16 + g * 4 + jj;
                        int pj = regionOf(wh * 8 + (j >> 3)) * 3 + regionOf(ww * 8 + (j & 7));
                        if (pi != pj) p[n][jj] -= MASK_L2E;
                    }
            }
            // no-max exp2 (S bounded; masked -> exp2(-144) = 0) + pack P^T
            #pragma unroll
            for (int n = 0; n < 4; ++n) {
                float e0 = __builtin_exp2f(p[n][0]);
                float e1 = __builtin_exp2f(p[n][1]);
                float e2 = __builtin_exp2f(p[n][2]);
                float e3 = __builtin_exp2f(p[n][3]);
                *(int2*)&pslab[l15 * 72 + n * 16 + g * 4] =
                    make_int2(pk2bf(e0, e1), pk2bf(e2, e3));
            }
            // O^T = V^T . P^T  (ones-row -> denominator at C row d=10)
            f32x4 pv = {0.f, 0.f, 0.f, 0.f};
            #pragma unroll
            for (int ks = 0; ks < 2; ++ks) {
                Frag pb2;
                pb2.i4 = *(const int4*)&pslab[l15 * 72 + ks * 32 + g * 8];
                pv = MFMA(va[ks].b8, pb2.b8, pv);
            }
            float denom = __int_as_float(__builtin_amdgcn_ds_bpermute(dl, __float_as_int(pv[2])));
            float rinv  = __builtin_amdgcn_rcpf(denom);

            int base = i_tok * 72 + h * 10;
            if (g == 0) {
                *(unsigned int*)&osb[base + 0] = pk2bf(pv[0] * rinv, pv[1] * rinv);
                *(unsigned int*)&osb[base + 2] = pk2bf(pv[2] * rinv, pv[3] * rinv);
            } else if (g == 1) {
                *(unsigned int*)&osb[base + 4] = pk2bf(pv[0] * rinv, pv[1] * rinv);
                *(unsigned int*)&osb[base + 6] = pk2bf(pv[2] * rinv, pv[3] * rinv);
            } else if (g == 2) {
                *(unsigned int*)&osb[base + 8] = pk2bf(pv[0] * rinv, pv[1] * rinv);
            }
        }
        h += 1; m0 = 0; mc = 6 - mc;
    }
    __syncthreads();

    // ---- phase 3: Y^T = Wp^T . O^T, float4 stores with reverse shift -------
    {
        const int4* wsp = (const int4*)(ws + WS_PROJF);
        Frag a0, a1;
        a0.i4 = wsp[(wid * 2 + 0) * 64 + lane];
        a1.i4 = wsp[(wid * 2 + 1) * 64 + lane];
        int c0 = wid * 16 + g * 4;
        float4 pbv = (c0 < 60) ? *(const float4*)&pbias[c0] : float4{0.f, 0.f, 0.f, 0.f};
        #pragma unroll
        for (int n = 0; n < 4; ++n) {
            Frag b0, b1;
            b0.i4 = *(const int4*)&osb[(n * 16 + l15) * 72 + g * 8];
            b1.i4 = *(const int4*)&osb[(n * 16 + l15) * 72 + 32 + g * 8];
            f32x4 acc = {0.f, 0.f, 0.f, 0.f};
            acc = MFMA(a0.b8, b0.b8, acc);
            acc = MFMA(a1.b8, b1.b8, acc);
            if (c0 < 60) {
                int tok = n * 16 + l15;
                int yi = tok >> 3, xi = tok & 7;
                int sh = wh * 8 + yi + 4; if (sh >= IMG) sh -= IMG;
                int sw = ww * 8 + xi + 4; if (sw >= IMG) sw -= IMG;
                float4 o = {acc[0] + pbv.x, acc[1] + pbv.y, acc[2] + pbv.z, acc[3] + pbv.w};
                *(float4*)&out[((b * IMG + sh) * IMG + sw) * CDIM + c0] = o;
            }
        }
    }
}

extern "C" void kernel_launch(void* const* d_in, const int* in_sizes, int n_in,
                              void* d_out, int out_size, void* d_ws, size_t ws_size,
                              hipStream_t stream) {
    const float* img  = (const float*)d_in[0];
    const float* qw   = (const float*)d_in[1];
    const float* bias = (const float*)d_in[2];
    const float* pw   = (const float*)d_in[3];
    const float* pb   = (const float*)d_in[4];
    float* out = (float*)d_out;

    swin_prep<<<107, 256, 0, stream>>>(qw, pw, bias, (unsigned char*)d_ws);
    swin_mfma<<<4 * WNUM, 256, 0, stream>>>(img, pb,
                                            (const unsigned char*)d_ws, out);
}

// Round 5
// 180.721 us; speedup vs baseline: 9.0402x; 1.0565x over previous
//
#include <hip/hip_runtime.h>
#include <hip/hip_bf16.h>

#define IMG    384
#define CDIM   60
#define NWIN   48
#define WNUM   (NWIN * NWIN)   // 2304

typedef short  bf16x8 __attribute__((ext_vector_type(8)));
typedef float  f32x4  __attribute__((ext_vector_type(4)));
union Frag { int4 i4; bf16x8 b8; };

#define MFMA(a, b, c) __builtin_amdgcn_mfma_f32_16x16x32_bf16((a), (b), (c), 0, 0, 0)

// d_ws layout
#define WS_QKVF  0        // 12 qk mtiles x 2 ks x 1KB = 24576 (A-frags, W rows)
#define WS_VF    24576    // 6 heads x 2 ks x 1KB      = 12288 (B-frags, W cols)
#define WS_PROJF 36864    // 4 x 2 x 1KB               = 8192  (A-frags)
#define WS_BIASF 45056    // [6][64][64] f32 (prescaled by log2e) = 98304

#define SCALE_L2E (0.31622776601683794f * 1.4426950408889634f)  // 1/sqrt(10)*log2(e)
#define MASK_L2E  144.26950408889634f                            // 100*log2(e)
#define LOG2E     1.4426950408889634f

__device__ __forceinline__ unsigned short f2bf(float f) {
    unsigned int u = __float_as_uint(f);
    unsigned int r = u + 0x7fffu + ((u >> 16) & 1u);
    return (unsigned short)(r >> 16);
}
__device__ __forceinline__ unsigned int pk2bf(float a, float b) {
    union { __hip_bfloat162 h; unsigned int u; } c;
    c.h = __float22bfloat162_rn(float2{a, b});
    return c.u;
}
__device__ __forceinline__ int regionOf(int x) {
    return (x < IMG - 8) ? 0 : ((x < IMG - 4) ? 1 : 2);
}
// all LDS buffers: 128B rows, XOR swizzle on byte bit 4 keyed by row&7
__device__ __forceinline__ int swz(int row, int byteoff) {
    return (row * 128 + byteoff) ^ ((row & 7) << 4);
}
// q/k packed row: [6 heads x 16B (d0-7)] at h*16, [6 x 4B (d8,d9)] at 96+h*4
__device__ __forceinline__ int4 qk_frag(const unsigned short* buf, int tok, int h, int g) {
    if (g == 0) return *(const int4*)((const char*)buf + swz(tok, h * 16));
    if (g == 1) {
        int v = *(const int*)((const char*)buf + swz(tok, 96 + h * 4));
        return int4{v, 0, 0, 0};
    }
    return int4{0, 0, 0, 0};
}

// ---------------------------------------------------------------------------
// Prep: weight frags (bf16) + f32 bias table (prescaled by log2e) in d_ws
// ---------------------------------------------------------------------------
__global__ void swin_prep(const float* __restrict__ qw,    // [60][180]
                          const float* __restrict__ pw,    // [60][60]
                          const float* __restrict__ bias,  // [225][6]
                          unsigned char* __restrict__ ws)
{
    int t = blockIdx.x * 256 + threadIdx.x;
    if (t < 1536) {                        // q/k A-frags: mt = h*2+type, f = mt*2+ks
        int lane = t & 63, f = t >> 6;
        int mt = f >> 1, ks = f & 1;
        int h = mt >> 1, type = mt & 1;
        int d = lane & 15, g8 = lane >> 4;
        unsigned short v8[8];
        #pragma unroll
        for (int jj = 0; jj < 8; ++jj) {
            int c = ks * 32 + g8 * 8 + jj;
            v8[jj] = f2bf((d < 10 && c < 60) ? qw[c * 180 + type * 60 + h * 10 + d] : 0.f);
        }
        int4 p;
        p.x = v8[0] | (v8[1] << 16);  p.y = v8[2] | (v8[3] << 16);
        p.z = v8[4] | (v8[5] << 16);  p.w = v8[6] | (v8[7] << 16);
        *(int4*)(ws + WS_QKVF + t * 16) = p;
    } else if (t < 2304) {                 // v B-frags: f = h*2+ks; col=d, k=c
        int t2 = t - 1536;
        int lane = t2 & 63, f = t2 >> 6;
        int h = f >> 1, ks = f & 1;
        int d = lane & 15, g8 = lane >> 4;
        unsigned short v8[8];
        #pragma unroll
        for (int jj = 0; jj < 8; ++jj) {
            int c = ks * 32 + g8 * 8 + jj;
            v8[jj] = f2bf((d < 10 && c < 60) ? qw[c * 180 + 120 + h * 10 + d] : 0.f);
        }
        int4 p;
        p.x = v8[0] | (v8[1] << 16);  p.y = v8[2] | (v8[3] << 16);
        p.z = v8[4] | (v8[5] << 16);  p.w = v8[6] | (v8[7] << 16);
        *(int4*)(ws + WS_VF + t2 * 16) = p;
    } else if (t < 2816) {                 // proj^T A-frags
        int t2 = t - 2304;
        int lane = t2 & 63, fq = t2 >> 6;
        int m = fq >> 1, ks = fq & 1;
        int c = m * 16 + (lane & 15);
        int g8 = lane >> 4;
        unsigned short v8[8];
        #pragma unroll
        for (int jj = 0; jj < 8; ++jj) {
            int cc = ks * 32 + g8 * 8 + jj;
            v8[jj] = f2bf((c < 60 && cc < 60) ? pw[cc * 60 + c] : 0.f);
        }
        int4 p;
        p.x = v8[0] | (v8[1] << 16);  p.y = v8[2] | (v8[3] << 16);
        p.z = v8[4] | (v8[5] << 16);  p.w = v8[6] | (v8[7] << 16);
        *(int4*)(ws + WS_PROJF + t2 * 16) = p;
    } else if (t < 2816 + 24576) {         // bias f32 table [6][i 64][j 64] * log2e
        int idx = t - 2816;
        int h = idx >> 12, r = idx & 4095;
        int i = r >> 6, j = r & 63;
        int yi = i >> 3, xi = i & 7, yj = j >> 3, xj = j & 7;
        int ridx = (yi - yj + 7) * 15 + (xi - xj + 7);
        ((float*)(ws + WS_BIASF))[h * 4096 + i * 64 + j] = bias[ridx * 6 + h] * LOG2E;
    }
}

// ---------------------------------------------------------------------------
// Main fused kernel: one 256-thread block per window, 3 barriers, 40.6 KB LDS
// ---------------------------------------------------------------------------
__global__ __launch_bounds__(256, 4)
void swin_mfma(const float* __restrict__ img,
               const float* __restrict__ pbias,   // [60]
               const unsigned char* __restrict__ ws,
               float* __restrict__ out)
{
    __shared__ __align__(16) unsigned short uni [64 * 64];  // xb / P-slabs [4][16][64]
    __shared__ __align__(16) unsigned short qall[64 * 64];  // packed-60 per tok
    __shared__ __align__(16) unsigned short kall[64 * 64];
    __shared__ __align__(16) unsigned short vall[61 * 64];  // rows h*10+d; row 60 = ones
    __shared__ __align__(16) unsigned short osb [64 * 64];  // [tok][h*10+d]; 60..63 = 0

    const int tid  = threadIdx.x;
    const int lane = tid & 63;
    const int wid  = __builtin_amdgcn_readfirstlane(tid >> 6);
    const int l15  = lane & 15;
    const int g    = lane >> 4;
    const int dl   = (32 + l15) << 2;         // bpermute lane for denominator

    const int bid = blockIdx.x;
    const int b   = bid / WNUM;
    const int wi  = bid - b * WNUM;
    const int wh  = wi / NWIN;
    const int ww  = wi - wh * NWIN;
    const bool boundary = (wh == NWIN - 1) || (ww == NWIN - 1);

    // ---- phase 0: load window (shift folded), token=lane, chunk=wid --------
    {
        int tok = lane;
        int yi = tok >> 3, xi = tok & 7;
        int sh = wh * 8 + yi + 4; if (sh >= IMG) sh -= IMG;
        int sw = ww * 8 + xi + 4; if (sw >= IMG) sw -= IMG;
        const float* src = img + ((size_t)(b * IMG + sh) * IMG + sw) * CDIM;
        #pragma unroll
        for (int it = 0; it < 4; ++it) {
            int cg = wid + it * 4;
            if (cg < 15) {
                float4 v = *(const float4*)(src + cg * 4);
                *(int2*)((char*)uni + swz(tok, cg * 8)) =
                    make_int2(pk2bf(v.x, v.y), pk2bf(v.z, v.w));
            } else {
                *(int2*)((char*)uni + swz(tok, 120)) = make_int2(0, 0);
            }
        }
    }
    if (tid < 128) {                           // osb cols 60..63 := 0
        int row = tid >> 1, half = tid & 1;
        *(unsigned int*)((char*)osb + swz(row, 120 + half * 4)) = 0u;
    }
    if (tid < 32) {                            // vall ones-row (row 60)
        *(unsigned int*)((char*)vall + swz(60, tid * 4)) = 0x3F803F80u;
    }
    __syncthreads();

    // ---- phase 1: QKV^T (12 q/k mtiles: 3/wave; 6 v heads: wave<2 gets 2) --
    {
        Frag xb[4][2];
        #pragma unroll
        for (int n = 0; n < 4; ++n)
            #pragma unroll
            for (int ks = 0; ks < 2; ++ks)
                xb[n][ks].i4 = *(const int4*)((const char*)uni + swz(n * 16 + l15, ks * 64 + g * 16));

        const int4* wsq = (const int4*)(ws + WS_QKVF);
        #pragma unroll
        for (int kk = 0; kk < 3; ++kk) {
            int mt = wid + kk * 4;             // uniform
            int h = mt >> 1, type = mt & 1;
            Frag a0, a1;
            a0.i4 = wsq[(mt * 2 + 0) * 64 + lane];
            a1.i4 = wsq[(mt * 2 + 1) * 64 + lane];
            unsigned short* dst = type ? kall : qall;
            #pragma unroll
            for (int n = 0; n < 4; ++n) {
                f32x4 acc = {0.f, 0.f, 0.f, 0.f};
                acc = MFMA(a0.b8, xb[n][0].b8, acc);
                acc = MFMA(a1.b8, xb[n][1].b8, acc);
                int tok = n * 16 + l15;
                unsigned pk01 = pk2bf(acc[0], acc[1]);
                unsigned pk23 = pk2bf(acc[2], acc[3]);
                if (g < 2)
                    *(int2*)((char*)dst + swz(tok, h * 16 + g * 8)) = make_int2(pk01, pk23);
                else if (g == 2)
                    *(unsigned*)((char*)dst + swz(tok, 96 + h * 4)) = pk01;  // d8,d9
            }
        }
        // V untransposed-write: A = X (xb), B = Wv  -> C[tok][d]
        const int4* wsv = (const int4*)(ws + WS_VF);
        int nv = (wid < 2) ? 2 : 1;
        #pragma unroll 1
        for (int kk = 0; kk < nv; ++kk) {
            int hv = wid + kk * 4;             // covers h 0..5
            Frag b0, b1;
            b0.i4 = wsv[(hv * 2 + 0) * 64 + lane];
            b1.i4 = wsv[(hv * 2 + 1) * 64 + lane];
            #pragma unroll
            for (int n = 0; n < 4; ++n) {
                f32x4 acc = {0.f, 0.f, 0.f, 0.f};
                acc = MFMA(xb[n][0].b8, b0.b8, acc);
                acc = MFMA(xb[n][1].b8, b1.b8, acc);
                // lane: col d = l15, rows = tokens n*16 + g*4 + 0..3
                if (l15 < 10) {
                    *(int2*)((char*)vall + swz(hv * 10 + l15, n * 32 + g * 8)) =
                        make_int2(pk2bf(acc[0], acc[1]), pk2bf(acc[2], acc[3]));
                }
            }
        }
    }
    __syncthreads();

    // ---- phase 2: attention, h-grouped (frag hoisting), no-max softmax -----
    const int prow = wid * 16 + l15;           // this wave's P-slab row in uni
    const float* biasf = (const float*)(ws + WS_BIASF);

    int h  = wid + (wid >> 1);                 // first head of this wave
    int m0 = (wid & 1) * 2;
    int mc = 4 - (wid & 1) * 2;
    #pragma unroll 1
    for (int grp = 0; grp < 2; ++grp) {
        // hoisted K-fragments for this head (packed-60, reg-constructed masks)
        Frag kb[4];
        #pragma unroll
        for (int n = 0; n < 4; ++n)
            kb[n].i4 = qk_frag(kall, n * 16 + l15, h, g);
        // hoisted V-fragments (row 60 = ones gives denominator at C row 10)
        int vrow = (l15 < 10) ? h * 10 + l15 : 60;
        Frag va[2];
        #pragma unroll
        for (int ks = 0; ks < 2; ++ks)
            va[ks].i4 = *(const int4*)((const char*)vall + swz(vrow, ks * 64 + g * 16));

        #pragma unroll 1
        for (int m = m0; m < m0 + mc; ++m) {
            int i_tok = m * 16 + l15;
            Frag qa;
            qa.i4 = qk_frag(qall, i_tok, h, g);

            f32x4 sacc[4];
            #pragma unroll
            for (int n = 0; n < 4; ++n) {
                f32x4 zz = {0.f, 0.f, 0.f, 0.f};
                sacc[n] = MFMA(kb[n].b8, qa.b8, zz);   // S^T: col=i, rows=j
            }
            // bias (f32, prescaled by log2e) + scale
            const float* bp = biasf + ((h << 6) + i_tok) * 64;
            float p[4][4];
            #pragma unroll
            for (int n = 0; n < 4; ++n) {
                float4 bb = *(const float4*)(bp + n * 16 + (g << 2));
                p[n][0] = fmaf(sacc[n][0], SCALE_L2E, bb.x);
                p[n][1] = fmaf(sacc[n][1], SCALE_L2E, bb.y);
                p[n][2] = fmaf(sacc[n][2], SCALE_L2E, bb.z);
                p[n][3] = fmaf(sacc[n][3], SCALE_L2E, bb.w);
            }
            if (boundary) {
                int pi = regionOf(wh * 8 + (i_tok >> 3)) * 3 + regionOf(ww * 8 + (i_tok & 7));
                #pragma unroll
                for (int n = 0; n < 4; ++n)
                    #pragma unroll
                    for (int jj = 0; jj < 4; ++jj) {
                        int j = n * 16 + g * 4 + jj;
                        int pj = regionOf(wh * 8 + (j >> 3)) * 3 + regionOf(ww * 8 + (j & 7));
                        if (pi != pj) p[n][jj] -= MASK_L2E;
                    }
            }
            // no-max exp2 (S bounded; masked -> exp2(-144) = 0), pack P^T
            #pragma unroll
            for (int n = 0; n < 4; ++n) {
                float e0 = __builtin_exp2f(p[n][0]);
                float e1 = __builtin_exp2f(p[n][1]);
                float e2 = __builtin_exp2f(p[n][2]);
                float e3 = __builtin_exp2f(p[n][3]);
                *(int2*)((char*)uni + swz(prow, n * 32 + g * 8)) =
                    make_int2(pk2bf(e0, e1), pk2bf(e2, e3));
            }
            // O^T = V^T . P^T  (ones-row -> denominator at C row 10)
            f32x4 pv = {0.f, 0.f, 0.f, 0.f};
            #pragma unroll
            for (int ks = 0; ks < 2; ++ks) {
                Frag pb2;
                pb2.i4 = *(const int4*)((const char*)uni + swz(prow, ks * 64 + g * 16));
                pv = MFMA(va[ks].b8, pb2.b8, pv);
            }
            float denom = __int_as_float(__builtin_amdgcn_ds_bpermute(dl, __float_as_int(pv[2])));
            float rinv  = __builtin_amdgcn_rcpf(denom);

            // write O rows d = g*4+jj at col i_tok (packed h*10+d)
            unsigned q01 = pk2bf(pv[0] * rinv, pv[1] * rinv);
            unsigned q23 = pk2bf(pv[2] * rinv, pv[3] * rinv);
            if (g < 2) {
                *(unsigned*)((char*)osb + swz(i_tok, h * 20 + g * 8 + 0)) = q01;
                *(unsigned*)((char*)osb + swz(i_tok, h * 20 + g * 8 + 4)) = q23;
            } else if (g == 2) {
                *(unsigned*)((char*)osb + swz(i_tok, h * 20 + 16)) = q01;  // d8,d9
            }
        }
        h += 1; m0 = 0; mc = 6 - mc;
    }
    __syncthreads();

    // ---- phase 3: Y^T = Wp^T . O^T, float4 stores with reverse shift -------
    {
        const int4* wsp = (const int4*)(ws + WS_PROJF);
        Frag a0, a1;
        a0.i4 = wsp[(wid * 2 + 0) * 64 + lane];
        a1.i4 = wsp[(wid * 2 + 1) * 64 + lane];
        int c0 = wid * 16 + g * 4;
        float4 pbv = (c0 < 60) ? *(const float4*)&pbias[c0] : float4{0.f, 0.f, 0.f, 0.f};
        #pragma unroll
        for (int n = 0; n < 4; ++n) {
            Frag b0, b1;
            b0.i4 = *(const int4*)((const char*)osb + swz(n * 16 + l15, g * 16));
            b1.i4 = *(const int4*)((const char*)osb + swz(n * 16 + l15, 64 + g * 16));
            f32x4 acc = {0.f, 0.f, 0.f, 0.f};
            acc = MFMA(a0.b8, b0.b8, acc);
            acc = MFMA(a1.b8, b1.b8, acc);
            if (c0 < 60) {
                int tok = n * 16 + l15;
                int yi = tok >> 3, xi = tok & 7;
                int sh = wh * 8 + yi + 4; if (sh >= IMG) sh -= IMG;
                int sw = ww * 8 + xi + 4; if (sw >= IMG) sw -= IMG;
                float4 o = {acc[0] + pbv.x, acc[1] + pbv.y, acc[2] + pbv.z, acc[3] + pbv.w};
                *(float4*)&out[((b * IMG + sh) * IMG + sw) * CDIM + c0] = o;
            }
        }
    }
}

extern "C" void kernel_launch(void* const* d_in, const int* in_sizes, int n_in,
                              void* d_out, int out_size, void* d_ws, size_t ws_size,
                              hipStream_t stream) {
    const float* img  = (const float*)d_in[0];
    const float* qw   = (const float*)d_in[1];
    const float* bias = (const float*)d_in[2];
    const float* pw   = (const float*)d_in[3];
    const float* pb   = (const float*)d_in[4];
    float* out = (float*)d_out;

    swin_prep<<<107, 256, 0, stream>>>(qw, pw, bias, (unsigned char*)d_ws);
    swin_mfma<<<4 * WNUM, 256, 0, stream>>>(img, pb,
                                            (const unsigned char*)d_ws, out);
}